// Round 7
// baseline (3427.969 us; speedup 1.0000x reference)
//
#include <hip/hip_runtime.h>
#include <hip/hip_bf16.h>

typedef __bf16 bf16_t;
typedef bf16_t bf16x4 __attribute__((ext_vector_type(4)));
typedef bf16_t bf16x8 __attribute__((ext_vector_type(8)));
typedef float f32x4 __attribute__((ext_vector_type(4)));

static constexpr int N_NODES = 50000;
static constexpr int N_EDGES = 1600000;
static constexpr int FIN = 1280;
static constexpr int HD = 128;
static constexpr int NG = 64;
// 0.5/sqrt(pi)/sqrt(128)
static constexpr float TP_NORM_F = 0.0249338908f;

// ---- fused transpose+scale+cast of the three weight matrices
__global__ __launch_bounds__(256) void k_transpose_all(const float* __restrict__ lin_w,
                                                       const float* __restrict__ tp_w1,
                                                       const float* __restrict__ tp_w2,
                                                       bf16_t* __restrict__ WtL,
                                                       bf16_t* __restrict__ Wt1,
                                                       bf16_t* __restrict__ Wt2) {
  int idx = blockIdx.x * 256 + threadIdx.x;
  const int A1 = FIN * HD;        // 163840
  const int A2 = A1 + HD * HD;    // +16384
  const int A3 = A2 + HD * HD;
  if (idx < A1) {
    int k = idx >> 7, n = idx & 127;
    WtL[n * FIN + k] = (bf16_t)lin_w[idx];
  } else if (idx < A2) {
    int j = idx - A1;
    int k = j >> 7, n = j & 127;
    Wt1[n * HD + k] = (bf16_t)(tp_w1[j] * TP_NORM_F);
  } else if (idx < A3) {
    int j = idx - A2;
    int k = j >> 7, n = j & 127;
    Wt2[n * HD + k] = (bf16_t)(tp_w2[j] * TP_NORM_F);
  }
}

// ---- GEMM1: C[M x 128] = relu(A[M x K] @ Bt^T + bias), A fp32.
// 32x128 block tile, 4 waves x (32x32), BK=64, XOR-swizzled LDS.
// Prefetch DISTANCE 2: reg->LDS store at iter `it` consumes global loads
// issued at iter it-1 (a full K-step earlier) -> HBM latency fully covered.
__global__ __launch_bounds__(256) void k_gemm1(const float* __restrict__ A,
                                               const bf16_t* __restrict__ Bt,
                                               const float* __restrict__ bias,
                                               bf16_t* __restrict__ C,
                                               int M, int K) {
  __shared__ bf16_t As[2][32 * 64];
  __shared__ bf16_t Bs[2][128 * 64];
  const int t = threadIdx.x;
  const int wid = t >> 6;
  const int lane = t & 63;
  const int wn = wid * 32;
  const int l15 = lane & 15;
  const int quad = lane >> 4;
  const int rowBase = blockIdx.x * 32;

  f32x4 acc[2][2];
#pragma unroll
  for (int i = 0; i < 2; ++i)
#pragma unroll
    for (int j = 0; j < 2; ++j) {
      f32x4 z = {0.f, 0.f, 0.f, 0.f};
      acc[i][j] = z;
    }

  // two register staging sets (prefetch distance 2)
  float4 aF[2][2];
  bf16x8 bR[2][4];

  auto loadAB = [&](int rs, int k0) {
#pragma unroll
    for (int i = 0; i < 2; ++i) {
      int idx = t + i * 256;
      int row = idx >> 4;   // 0..31
      int col4 = idx & 15;  // float4 units
      int gr = rowBase + row;
      aF[rs][i] = make_float4(0.f, 0.f, 0.f, 0.f);
      if (gr < M) aF[rs][i] = *(const float4*)(A + (size_t)gr * K + k0 + col4 * 4);
    }
#pragma unroll
    for (int i = 0; i < 4; ++i) {
      int idx = t + i * 256;
      int row = idx >> 3;  // 0..127
      int c = idx & 7;
      bR[rs][i] = *(const bf16x8*)(Bt + (size_t)row * K + k0 + c * 8);
    }
  };
  auto storeAB = [&](int rs, int buf) {
#pragma unroll
    for (int i = 0; i < 2; ++i) {
      int idx = t + i * 256;
      int row = idx >> 4;
      int col4 = idx & 15;
      bf16x4 w;
      w[0] = (bf16_t)aF[rs][i].x; w[1] = (bf16_t)aF[rs][i].y;
      w[2] = (bf16_t)aF[rs][i].z; w[3] = (bf16_t)aF[rs][i].w;
      int c = col4 >> 1;
      int off = row * 64 + ((c ^ (row & 7)) << 3) + ((col4 & 1) << 2);
      *(bf16x4*)&As[buf][off] = w;
    }
#pragma unroll
    for (int i = 0; i < 4; ++i) {
      int idx = t + i * 256;
      int row = idx >> 3;
      int c = idx & 7;
      int off = row * 64 + ((c ^ (row & 7)) << 3);
      *(bf16x8*)&Bs[buf][off] = bR[rs][i];
    }
  };
  auto compute = [&](int buf) {
#pragma unroll
    for (int kk = 0; kk < 2; ++kk) {
      bf16x8 af[2], bfr[2];
      int k8 = kk * 4 + quad;
#pragma unroll
      for (int mi = 0; mi < 2; ++mi) {
        int row = mi * 16 + l15;
        af[mi] = *(const bf16x8*)&As[buf][row * 64 + ((k8 ^ (row & 7)) << 3)];
      }
#pragma unroll
      for (int ni = 0; ni < 2; ++ni) {
        int row = wn + ni * 16 + l15;
        bfr[ni] = *(const bf16x8*)&Bs[buf][row * 64 + ((k8 ^ (row & 7)) << 3)];
      }
#pragma unroll
      for (int mi = 0; mi < 2; ++mi)
#pragma unroll
        for (int ni = 0; ni < 2; ++ni)
          acc[mi][ni] = __builtin_amdgcn_mfma_f32_16x16x32_bf16(af[mi], bfr[ni], acc[mi][ni], 0, 0, 0);
    }
  };

  const int nIter = K >> 6;  // 20 for K=1280
  loadAB(0, 0);
  storeAB(0, 0);        // waits vmcnt on set 0 only
  loadAB(1, 64);        // prefetch iter 1 (in flight across barrier)
  __syncthreads();
  for (int it = 0; it < nIter; ++it) {
    int cur = it & 1;
    if (it + 2 < nIter) loadAB(cur, (it + 2) << 6);  // reg set `cur` is free
    compute(cur);
    if (it + 1 < nIter) storeAB(cur ^ 1, cur ^ 1);   // consumes loads from it-1
    __syncthreads();
  }

  // epilogue: C/D layout col=lane&15, row=quad*4+reg (m89-verified)
#pragma unroll
  for (int mi = 0; mi < 2; ++mi) {
#pragma unroll
    for (int ni = 0; ni < 2; ++ni) {
      int col = wn + ni * 16 + l15;
      float bv = bias[col];
#pragma unroll
      for (int r = 0; r < 4; ++r) {
        int row = mi * 16 + quad * 4 + r;
        int gr = rowBase + row;
        if (gr < M) {
          float v = fmaxf(acc[mi][ni][r] + bv, 0.f);
          C[(size_t)gr * HD + col] = (bf16_t)v;
        }
      }
    }
  }
}

// ---- Conv GEMM: C[M x 128] = act(A[M x 128] @ Bt^T), A bf16, K=128 fixed.
// Whole B (32 KB) + A-tile (8 KB) staged once; ONE barrier; 16 MFMAs/wave.
__global__ __launch_bounds__(256) void k_gemm_conv(const bf16_t* __restrict__ A,
                                                   const bf16_t* __restrict__ Bt,
                                                   bf16_t* __restrict__ C,
                                                   int M, int doRelu) {
  __shared__ bf16_t As[32 * 128];
  __shared__ bf16_t Bs[128 * 128];
  const int t = threadIdx.x;
  const int wid = t >> 6;
  const int lane = t & 63;
  const int wn = wid * 32;
  const int l15 = lane & 15;
  const int quad = lane >> 4;
  const int rowBase = blockIdx.x * 32;

  // stage B: 128x128 bf16 = 2048 chunks of 8 -> 8 per thread
#pragma unroll
  for (int i = 0; i < 8; ++i) {
    int idx = t + i * 256;
    int row = idx >> 4;   // 0..127
    int c = idx & 15;     // 16B chunk
    bf16x8 v = *(const bf16x8*)(Bt + (size_t)row * HD + c * 8);
    *(bf16x8*)&Bs[row * 128 + ((c ^ (row & 7)) << 3)] = v;
  }
  // stage A: 32x128 = 512 chunks -> 2 per thread
#pragma unroll
  for (int i = 0; i < 2; ++i) {
    int idx = t + i * 256;
    int row = idx >> 4;   // 0..31
    int c = idx & 15;
    int gr = rowBase + row;
    bf16x8 v = {};
    if (gr < M) v = *(const bf16x8*)(A + (size_t)gr * HD + c * 8);
    *(bf16x8*)&As[row * 128 + ((c ^ (row & 7)) << 3)] = v;
  }
  __syncthreads();

  f32x4 acc[2][2];
#pragma unroll
  for (int i = 0; i < 2; ++i)
#pragma unroll
    for (int j = 0; j < 2; ++j) {
      f32x4 z = {0.f, 0.f, 0.f, 0.f};
      acc[i][j] = z;
    }

#pragma unroll
  for (int kk = 0; kk < 4; ++kk) {
    bf16x8 af[2], bfr[2];
    int k8 = kk * 4 + quad;
#pragma unroll
    for (int mi = 0; mi < 2; ++mi) {
      int row = mi * 16 + l15;
      af[mi] = *(const bf16x8*)&As[row * 128 + ((k8 ^ (row & 7)) << 3)];
    }
#pragma unroll
    for (int ni = 0; ni < 2; ++ni) {
      int row = wn + ni * 16 + l15;
      bfr[ni] = *(const bf16x8*)&Bs[row * 128 + ((k8 ^ (row & 7)) << 3)];
    }
#pragma unroll
    for (int mi = 0; mi < 2; ++mi)
#pragma unroll
      for (int ni = 0; ni < 2; ++ni)
        acc[mi][ni] = __builtin_amdgcn_mfma_f32_16x16x32_bf16(af[mi], bfr[ni], acc[mi][ni], 0, 0, 0);
  }

#pragma unroll
  for (int mi = 0; mi < 2; ++mi) {
#pragma unroll
    for (int ni = 0; ni < 2; ++ni) {
      int col = wn + ni * 16 + l15;
#pragma unroll
      for (int r = 0; r < 4; ++r) {
        int row = mi * 16 + quad * 4 + r;
        int gr = rowBase + row;
        if (gr < M) {
          float v = acc[mi][ni][r];
          if (doRelu) v = fmaxf(v, 0.f);
          C[(size_t)gr * HD + col] = (bf16_t)v;
        }
      }
    }
  }
}

// ---- CSR build: pass1 computes per-edge slot via one atomic (also yields counts)
__global__ __launch_bounds__(256) void k_pos(const int* __restrict__ dst, int* __restrict__ cnt,
                                             int* __restrict__ pos, int E) {
  int e = blockIdx.x * 256 + threadIdx.x;
  if (e < E) pos[e] = atomicAdd(&cnt[dst[e]], 1);
}

// hierarchical scan
__global__ __launch_bounds__(256) void k_scan1(const int* __restrict__ cnt, int* __restrict__ bsum, int n) {
  __shared__ int s[256];
  int t = threadIdx.x;
  int i = blockIdx.x * 256 + t;
  s[t] = (i < n) ? cnt[i] : 0;
  __syncthreads();
  for (int d = 128; d > 0; d >>= 1) {
    if (t < d) s[t] += s[t + d];
    __syncthreads();
  }
  if (t == 0) bsum[blockIdx.x] = s[0];
}

__global__ __launch_bounds__(256) void k_scan2(int* __restrict__ bsum, int nb) {
  __shared__ int s[256];
  int t = threadIdx.x;
  int v = (t < nb) ? bsum[t] : 0;
  s[t] = v;
  __syncthreads();
  for (int d = 1; d < 256; d <<= 1) {
    int x = (t >= d) ? s[t - d] : 0;
    __syncthreads();
    s[t] += x;
    __syncthreads();
  }
  if (t < nb) bsum[t] = s[t] - v;  // exclusive
  if (t == 255) bsum[nb] = s[255]; // total
}

__global__ __launch_bounds__(256) void k_scan3(const int* __restrict__ cnt, const int* __restrict__ bsum,
                                               int* __restrict__ off, int n) {
  __shared__ int s[256];
  int t = threadIdx.x;
  int i = blockIdx.x * 256 + t;
  int v = (i < n) ? cnt[i] : 0;
  s[t] = v;
  __syncthreads();
  for (int d = 1; d < 256; d <<= 1) {
    int x = (t >= d) ? s[t - d] : 0;
    __syncthreads();
    s[t] += x;
    __syncthreads();
  }
  if (i < n) off[i] = bsum[blockIdx.x] + s[t] - v;
  if (i == n - 1) off[n] = bsum[blockIdx.x] + s[t];
}

__global__ __launch_bounds__(256) void k_fill(const int* __restrict__ src, const int* __restrict__ dst,
                                              const int* __restrict__ off, const int* __restrict__ pos,
                                              int* __restrict__ ssrc, int E) {
  int e = blockIdx.x * 256 + threadIdx.x;
  if (e >= E) return;
  ssrc[off[dst[e]] + pos[e]] = src[e];
}

// ---- CSR mean-aggregate, wave-per-node: 4 lane-groups x 16 lanes (r5 version).
__global__ __launch_bounds__(256) void k_aggregate(const bf16_t* __restrict__ h,
                                                   const int* __restrict__ ssrc,
                                                   const int* __restrict__ off,
                                                   bf16_t* __restrict__ agg, int n) {
  int node = blockIdx.x * 4 + (threadIdx.x >> 6);
  if (node >= n) return;
  int lane = threadIdx.x & 63;
  int g = lane >> 4;
  int fl = lane & 15;
  int b = off[node], e = off[node + 1];
  float acc[8];
#pragma unroll
  for (int j = 0; j < 8; ++j) acc[j] = 0.f;
  const bf16_t* hp = h + fl * 8;
  int i = b;
  for (; i + 16 <= e; i += 16) {
    int s0 = ssrc[i + g], s1 = ssrc[i + 4 + g], s2 = ssrc[i + 8 + g], s3 = ssrc[i + 12 + g];
    bf16x8 v0 = *(const bf16x8*)(hp + (size_t)s0 * HD);
    bf16x8 v1 = *(const bf16x8*)(hp + (size_t)s1 * HD);
    bf16x8 v2 = *(const bf16x8*)(hp + (size_t)s2 * HD);
    bf16x8 v3 = *(const bf16x8*)(hp + (size_t)s3 * HD);
#pragma unroll
    for (int j = 0; j < 8; ++j)
      acc[j] += ((float)v0[j] + (float)v1[j]) + ((float)v2[j] + (float)v3[j]);
  }
  if (i + 8 <= e) {
    int s0 = ssrc[i + g], s1 = ssrc[i + 4 + g];
    bf16x8 v0 = *(const bf16x8*)(hp + (size_t)s0 * HD);
    bf16x8 v1 = *(const bf16x8*)(hp + (size_t)s1 * HD);
#pragma unroll
    for (int j = 0; j < 8; ++j) acc[j] += (float)v0[j] + (float)v1[j];
    i += 8;
  }
  if (i + 4 <= e) {
    int s0 = ssrc[i + g];
    bf16x8 v0 = *(const bf16x8*)(hp + (size_t)s0 * HD);
#pragma unroll
    for (int j = 0; j < 8; ++j) acc[j] += (float)v0[j];
    i += 4;
  }
  if (i + g < e) {
    int s0 = ssrc[i + g];
    bf16x8 v0 = *(const bf16x8*)(hp + (size_t)s0 * HD);
#pragma unroll
    for (int j = 0; j < 8; ++j) acc[j] += (float)v0[j];
  }
#pragma unroll
  for (int j = 0; j < 8; ++j) {
    acc[j] += __shfl_xor(acc[j], 16);
    acc[j] += __shfl_xor(acc[j], 32);
  }
  if (g == 0) {
    float inv = (e > b) ? 1.f / (float)(e - b) : 0.f;
    bf16x8 o;
#pragma unroll
    for (int j = 0; j < 8; ++j) o[j] = (bf16_t)(acc[j] * inv);
    *(bf16x8*)(agg + (size_t)node * HD + fl * 8) = o;
  }
}

// ---- pool: block-per-graph, binary-search boundaries, writes mean (no atomics)
__global__ __launch_bounds__(256) void k_pool(const bf16_t* __restrict__ agg,
                                              const int* __restrict__ batch,
                                              float* __restrict__ p, int n) {
  __shared__ float s[256];
  int g = blockIdx.x;
  int t = threadIdx.x;
  int lo = 0, hi = n;
  while (lo < hi) { int m = (lo + hi) >> 1; if (batch[m] < g) lo = m + 1; else hi = m; }
  int lo2 = lo, hi2 = n;
  while (lo2 < hi2) { int m = (lo2 + hi2) >> 1; if (batch[m] < g + 1) lo2 = m + 1; else hi2 = m; }
  int count = lo2 - lo;
  int f = t & 127;
  int half = t >> 7;
  float acc = 0.f;
  for (int i = lo + half; i < lo2; i += 2)
    acc += (float)agg[(size_t)i * HD + f];
  s[t] = acc;
  __syncthreads();
  if (t < 128) {
    float v = s[t] + s[t + 128];
    float inv = (count > 0) ? 1.f / (float)count : 0.f;
    p[g * HD + t] = v * inv;
  }
}

// ---- head: z = p @ (w3*norm); out = mlp(z). One block per graph.
__global__ __launch_bounds__(128) void k_head(const float* __restrict__ p,
                                              const float* __restrict__ w3,
                                              const float* __restrict__ c1w, const float* __restrict__ c1b,
                                              const float* __restrict__ c2w, const float* __restrict__ c2b,
                                              const float* __restrict__ c3w, const float* __restrict__ c3b,
                                              float* __restrict__ out) {
  __shared__ float sa[128], sb[128];
  int g = blockIdx.x, t = threadIdx.x;
  sa[t] = p[g * HD + t];
  __syncthreads();
  float z = 0.f;
  for (int k = 0; k < HD; ++k) z += sa[k] * w3[k * HD + t];
  z *= TP_NORM_F;
  out[128 + g * HD + t] = z;
  sb[t] = z;
  __syncthreads();
  float o1 = c1b[t];
  for (int k = 0; k < HD; ++k) o1 += sb[k] * c1w[k * HD + t];
  o1 = fmaxf(o1, 0.f);
  __syncthreads();
  sa[t] = o1;
  __syncthreads();
  float o2 = c2b[t];
  for (int k = 0; k < HD; ++k) o2 += sa[k] * c2w[k * HD + t];
  o2 = fmaxf(o2, 0.f);
  __syncthreads();
  sb[t] = o2;
  __syncthreads();
  if (t < 2) {
    float o = c3b[t];
    for (int k = 0; k < HD; ++k) o += sb[k] * c3w[k * 2 + t];
    out[g * 2 + t] = o;
  }
}

extern "C" void kernel_launch(void* const* d_in, const int* in_sizes, int n_in,
                              void* d_out, int out_size, void* d_ws, size_t ws_size,
                              hipStream_t stream) {
  const float* x = (const float*)d_in[0];
  const int* eidx = (const int*)d_in[2];
  const int* src = eidx;
  const int* dst = eidx + N_EDGES;
  const int* batch = (const int*)d_in[3];
  const float* lin_w = (const float*)d_in[4];
  const float* lin_b = (const float*)d_in[5];
  const float* tp_w1 = (const float*)d_in[6];
  const float* tp_w2 = (const float*)d_in[7];
  const float* tp_w3 = (const float*)d_in[8];
  const float* c1w = (const float*)d_in[9];
  const float* c1b = (const float*)d_in[10];
  const float* c2w = (const float*)d_in[11];
  const float* c2b = (const float*)d_in[12];
  const float* c3w = (const float*)d_in[13];
  const float* c3b = (const float*)d_in[14];
  float* out = (float*)d_out;
  (void)in_sizes; (void)n_in; (void)out_size; (void)ws_size;

  uintptr_t wp = (uintptr_t)d_ws;
  auto alloc = [&](size_t bytes) -> void* {
    uintptr_t a = (wp + 255) & ~(uintptr_t)255;
    wp = a + bytes;
    return (void*)a;
  };
  bf16_t* WtL  = (bf16_t*)alloc(sizeof(bf16_t) * (size_t)HD * FIN);
  bf16_t* Wt1  = (bf16_t*)alloc(sizeof(bf16_t) * (size_t)HD * HD);
  bf16_t* Wt2  = (bf16_t*)alloc(sizeof(bf16_t) * (size_t)HD * HD);
  bf16_t* h    = (bf16_t*)alloc(sizeof(bf16_t) * (size_t)50048 * HD);
  bf16_t* agg  = (bf16_t*)alloc(sizeof(bf16_t) * (size_t)50048 * HD);
  int*    cnt  = (int*)alloc(sizeof(int) * N_NODES);
  int*    bsum = (int*)alloc(sizeof(int) * 256);
  int*    offs = (int*)alloc(sizeof(int) * (N_NODES + 1));
  int*    pos  = (int*)alloc(sizeof(int) * N_EDGES);
  int*    ssrc = (int*)alloc(sizeof(int) * N_EDGES);
  float*  pbuf = (float*)alloc(sizeof(float) * NG * HD);

  hipMemsetAsync(cnt, 0, sizeof(int) * N_NODES, stream);

  k_transpose_all<<<(FIN * HD + 2 * HD * HD + 255) / 256, 256, 0, stream>>>(
      lin_w, tp_w1, tp_w2, WtL, Wt1, Wt2);

  const int nScanBlocks = (N_NODES + 255) / 256;  // 196
  k_pos<<<(N_EDGES + 255) / 256, 256, 0, stream>>>(dst, cnt, pos, N_EDGES);
  k_scan1<<<nScanBlocks, 256, 0, stream>>>(cnt, bsum, N_NODES);
  k_scan2<<<1, 256, 0, stream>>>(bsum, nScanBlocks);
  k_scan3<<<nScanBlocks, 256, 0, stream>>>(cnt, bsum, offs, N_NODES);
  k_fill<<<(N_EDGES + 255) / 256, 256, 0, stream>>>(src, dst, offs, pos, ssrc, N_EDGES);

  const int gblocks = (N_NODES + 31) / 32;   // 1563
  const int ablocks = (N_NODES + 3) / 4;     // 12500

  // h0 = relu(x @ lin_w + b)
  k_gemm1<<<gblocks, 256, 0, stream>>>(x, WtL, lin_b, h, N_NODES, FIN);

  // conv1
  k_aggregate<<<ablocks, 256, 0, stream>>>(h, ssrc, offs, agg, N_NODES);
  k_gemm_conv<<<gblocks, 256, 0, stream>>>(agg, Wt1, h, N_NODES, 1);
  // conv2
  k_aggregate<<<ablocks, 256, 0, stream>>>(h, ssrc, offs, agg, N_NODES);
  k_gemm_conv<<<gblocks, 256, 0, stream>>>(agg, Wt2, h, N_NODES, 1);
  // conv3 aggregation only (W3 folded into head)
  k_aggregate<<<ablocks, 256, 0, stream>>>(h, ssrc, offs, agg, N_NODES);

  k_pool<<<NG, 256, 0, stream>>>(agg, batch, pbuf, N_NODES);
  k_head<<<NG, 128, 0, stream>>>(pbuf, tp_w3, c1w, c1b, c2w, c2b, c3w, c3b, out);
}

// Round 8
// 802.436 us; speedup vs baseline: 4.2720x; 4.2720x over previous
//
#include <hip/hip_runtime.h>
#include <hip/hip_bf16.h>

typedef __bf16 bf16_t;
typedef bf16_t bf16x4 __attribute__((ext_vector_type(4)));
typedef bf16_t bf16x8 __attribute__((ext_vector_type(8)));
typedef float f32x4 __attribute__((ext_vector_type(4)));

static constexpr int N_NODES = 50000;
static constexpr int N_EDGES = 1600000;
static constexpr int FIN = 1280;
static constexpr int HD = 128;
static constexpr int NG = 64;
// 0.5/sqrt(pi)/sqrt(128)
static constexpr float TP_NORM_F = 0.0249338908f;

// ---- fused transpose+scale+cast of the three weight matrices
__global__ __launch_bounds__(256) void k_transpose_all(const float* __restrict__ lin_w,
                                                       const float* __restrict__ tp_w1,
                                                       const float* __restrict__ tp_w2,
                                                       bf16_t* __restrict__ WtL,
                                                       bf16_t* __restrict__ Wt1,
                                                       bf16_t* __restrict__ Wt2) {
  int idx = blockIdx.x * 256 + threadIdx.x;
  const int A1 = FIN * HD;        // 163840
  const int A2 = A1 + HD * HD;    // +16384
  const int A3 = A2 + HD * HD;
  if (idx < A1) {
    int k = idx >> 7, n = idx & 127;
    WtL[n * FIN + k] = (bf16_t)lin_w[idx];
  } else if (idx < A2) {
    int j = idx - A1;
    int k = j >> 7, n = j & 127;
    Wt1[n * HD + k] = (bf16_t)(tp_w1[j] * TP_NORM_F);
  } else if (idx < A3) {
    int j = idx - A2;
    int k = j >> 7, n = j & 127;
    Wt2[n * HD + k] = (bf16_t)(tp_w2[j] * TP_NORM_F);
  }
}

// ---- GEMM1: C[M x 128] = relu(A[M x K] @ Bt^T + bias), A fp32.
// 32x128 block tile, 4 waves x (32x32), BK=64, XOR-swizzled LDS.
// Prefetch distance 2 with STATICALLY-INDEXED register sets (two separate
// variable sets + K-loop unrolled x2) -- dynamic indexing spills to scratch.
__global__ __launch_bounds__(256) void k_gemm1(const float* __restrict__ A,
                                               const bf16_t* __restrict__ Bt,
                                               const float* __restrict__ bias,
                                               bf16_t* __restrict__ C,
                                               int M, int K) {
  __shared__ bf16_t As[2][32 * 64];
  __shared__ bf16_t Bs[2][128 * 64];
  const int t = threadIdx.x;
  const int wid = t >> 6;
  const int lane = t & 63;
  const int wn = wid * 32;
  const int l15 = lane & 15;
  const int quad = lane >> 4;
  const int rowBase = blockIdx.x * 32;

  f32x4 acc[2][2];
#pragma unroll
  for (int i = 0; i < 2; ++i)
#pragma unroll
    for (int j = 0; j < 2; ++j) {
      f32x4 z = {0.f, 0.f, 0.f, 0.f};
      acc[i][j] = z;
    }

  // two STATIC register staging sets (prefetch distance 2)
  float4 aF0[2], aF1[2];
  bf16x8 bR0[4], bR1[4];

  auto loadAB = [&](float4 (&aF)[2], bf16x8 (&bR)[4], int k0) {
#pragma unroll
    for (int i = 0; i < 2; ++i) {
      int idx = t + i * 256;
      int row = idx >> 4;   // 0..31
      int col4 = idx & 15;  // float4 units
      int gr = rowBase + row;
      aF[i] = make_float4(0.f, 0.f, 0.f, 0.f);
      if (gr < M) aF[i] = *(const float4*)(A + (size_t)gr * K + k0 + col4 * 4);
    }
#pragma unroll
    for (int i = 0; i < 4; ++i) {
      int idx = t + i * 256;
      int row = idx >> 3;  // 0..127
      int c = idx & 7;
      bR[i] = *(const bf16x8*)(Bt + (size_t)row * K + k0 + c * 8);
    }
  };
  auto storeAB = [&](const float4 (&aF)[2], const bf16x8 (&bR)[4], int buf) {
#pragma unroll
    for (int i = 0; i < 2; ++i) {
      int idx = t + i * 256;
      int row = idx >> 4;
      int col4 = idx & 15;
      bf16x4 w;
      w[0] = (bf16_t)aF[i].x; w[1] = (bf16_t)aF[i].y;
      w[2] = (bf16_t)aF[i].z; w[3] = (bf16_t)aF[i].w;
      int c = col4 >> 1;
      int off = row * 64 + ((c ^ (row & 7)) << 3) + ((col4 & 1) << 2);
      *(bf16x4*)&As[buf][off] = w;
    }
#pragma unroll
    for (int i = 0; i < 4; ++i) {
      int idx = t + i * 256;
      int row = idx >> 3;
      int c = idx & 7;
      int off = row * 64 + ((c ^ (row & 7)) << 3);
      *(bf16x8*)&Bs[buf][off] = bR[i];
    }
  };
  auto compute = [&](int buf) {
#pragma unroll
    for (int kk = 0; kk < 2; ++kk) {
      bf16x8 af[2], bfr[2];
      int k8 = kk * 4 + quad;
#pragma unroll
      for (int mi = 0; mi < 2; ++mi) {
        int row = mi * 16 + l15;
        af[mi] = *(const bf16x8*)&As[buf][row * 64 + ((k8 ^ (row & 7)) << 3)];
      }
#pragma unroll
      for (int ni = 0; ni < 2; ++ni) {
        int row = wn + ni * 16 + l15;
        bfr[ni] = *(const bf16x8*)&Bs[buf][row * 64 + ((k8 ^ (row & 7)) << 3)];
      }
#pragma unroll
      for (int mi = 0; mi < 2; ++mi)
#pragma unroll
        for (int ni = 0; ni < 2; ++ni)
          acc[mi][ni] = __builtin_amdgcn_mfma_f32_16x16x32_bf16(af[mi], bfr[ni], acc[mi][ni], 0, 0, 0);
    }
  };

  const int nIter = K >> 6;  // 20 for K=1280 (even)
  loadAB(aF0, bR0, 0);
  storeAB(aF0, bR0, 0);      // waits vmcnt on set 0 only
  loadAB(aF1, bR1, 64);      // prefetch iter 1 (stays in flight across barrier)
  __syncthreads();
  for (int it = 0; it < nIter; it += 2) {
    // even iter: compute buf0; prefetch it+2 into set0; store set1 -> buf1
    if (it + 2 < nIter) loadAB(aF0, bR0, (it + 2) << 6);
    compute(0);
    if (it + 1 < nIter) storeAB(aF1, bR1, 1);
    __syncthreads();
    // odd iter: compute buf1; prefetch it+3 into set1; store set0 -> buf0
    if (it + 3 < nIter) loadAB(aF1, bR1, (it + 3) << 6);
    if (it + 1 < nIter) compute(1);
    if (it + 2 < nIter) storeAB(aF0, bR0, 0);
    __syncthreads();
  }

  // epilogue: C/D layout col=lane&15, row=quad*4+reg (m89-verified)
#pragma unroll
  for (int mi = 0; mi < 2; ++mi) {
#pragma unroll
    for (int ni = 0; ni < 2; ++ni) {
      int col = wn + ni * 16 + l15;
      float bv = bias[col];
#pragma unroll
      for (int r = 0; r < 4; ++r) {
        int row = mi * 16 + quad * 4 + r;
        int gr = rowBase + row;
        if (gr < M) {
          float v = fmaxf(acc[mi][ni][r] + bv, 0.f);
          C[(size_t)gr * HD + col] = (bf16_t)v;
        }
      }
    }
  }
}

// ---- Conv GEMM: C[M x 128] = act(A[M x 128] @ Bt^T), A bf16, K=128 fixed.
// Whole B (32 KB) + A-tile (8 KB) staged once; ONE barrier; 16 MFMAs/wave.
__global__ __launch_bounds__(256) void k_gemm_conv(const bf16_t* __restrict__ A,
                                                   const bf16_t* __restrict__ Bt,
                                                   bf16_t* __restrict__ C,
                                                   int M, int doRelu) {
  __shared__ bf16_t As[32 * 128];
  __shared__ bf16_t Bs[128 * 128];
  const int t = threadIdx.x;
  const int wid = t >> 6;
  const int lane = t & 63;
  const int wn = wid * 32;
  const int l15 = lane & 15;
  const int quad = lane >> 4;
  const int rowBase = blockIdx.x * 32;

  // stage B: 128x128 bf16 = 2048 chunks of 8 -> 8 per thread
#pragma unroll
  for (int i = 0; i < 8; ++i) {
    int idx = t + i * 256;
    int row = idx >> 4;   // 0..127
    int c = idx & 15;     // 16B chunk
    bf16x8 v = *(const bf16x8*)(Bt + (size_t)row * HD + c * 8);
    *(bf16x8*)&Bs[row * 128 + ((c ^ (row & 7)) << 3)] = v;
  }
  // stage A: 32x128 = 512 chunks -> 2 per thread
#pragma unroll
  for (int i = 0; i < 2; ++i) {
    int idx = t + i * 256;
    int row = idx >> 4;   // 0..31
    int c = idx & 15;
    int gr = rowBase + row;
    bf16x8 v = {};
    if (gr < M) v = *(const bf16x8*)(A + (size_t)gr * HD + c * 8);
    *(bf16x8*)&As[row * 128 + ((c ^ (row & 7)) << 3)] = v;
  }
  __syncthreads();

  f32x4 acc[2][2];
#pragma unroll
  for (int i = 0; i < 2; ++i)
#pragma unroll
    for (int j = 0; j < 2; ++j) {
      f32x4 z = {0.f, 0.f, 0.f, 0.f};
      acc[i][j] = z;
    }

#pragma unroll
  for (int kk = 0; kk < 4; ++kk) {
    bf16x8 af[2], bfr[2];
    int k8 = kk * 4 + quad;
#pragma unroll
    for (int mi = 0; mi < 2; ++mi) {
      int row = mi * 16 + l15;
      af[mi] = *(const bf16x8*)&As[row * 128 + ((k8 ^ (row & 7)) << 3)];
    }
#pragma unroll
    for (int ni = 0; ni < 2; ++ni) {
      int row = wn + ni * 16 + l15;
      bfr[ni] = *(const bf16x8*)&Bs[row * 128 + ((k8 ^ (row & 7)) << 3)];
    }
#pragma unroll
    for (int mi = 0; mi < 2; ++mi)
#pragma unroll
      for (int ni = 0; ni < 2; ++ni)
        acc[mi][ni] = __builtin_amdgcn_mfma_f32_16x16x32_bf16(af[mi], bfr[ni], acc[mi][ni], 0, 0, 0);
  }

#pragma unroll
  for (int mi = 0; mi < 2; ++mi) {
#pragma unroll
    for (int ni = 0; ni < 2; ++ni) {
      int col = wn + ni * 16 + l15;
#pragma unroll
      for (int r = 0; r < 4; ++r) {
        int row = mi * 16 + quad * 4 + r;
        int gr = rowBase + row;
        if (gr < M) {
          float v = acc[mi][ni][r];
          if (doRelu) v = fmaxf(v, 0.f);
          C[(size_t)gr * HD + col] = (bf16_t)v;
        }
      }
    }
  }
}

// ---- CSR build: pass1 computes per-edge slot via one atomic (also yields counts)
__global__ __launch_bounds__(256) void k_pos(const int* __restrict__ dst, int* __restrict__ cnt,
                                             int* __restrict__ pos, int E) {
  int e = blockIdx.x * 256 + threadIdx.x;
  if (e < E) pos[e] = atomicAdd(&cnt[dst[e]], 1);
}

// hierarchical scan
__global__ __launch_bounds__(256) void k_scan1(const int* __restrict__ cnt, int* __restrict__ bsum, int n) {
  __shared__ int s[256];
  int t = threadIdx.x;
  int i = blockIdx.x * 256 + t;
  s[t] = (i < n) ? cnt[i] : 0;
  __syncthreads();
  for (int d = 128; d > 0; d >>= 1) {
    if (t < d) s[t] += s[t + d];
    __syncthreads();
  }
  if (t == 0) bsum[blockIdx.x] = s[0];
}

__global__ __launch_bounds__(256) void k_scan2(int* __restrict__ bsum, int nb) {
  __shared__ int s[256];
  int t = threadIdx.x;
  int v = (t < nb) ? bsum[t] : 0;
  s[t] = v;
  __syncthreads();
  for (int d = 1; d < 256; d <<= 1) {
    int x = (t >= d) ? s[t - d] : 0;
    __syncthreads();
    s[t] += x;
    __syncthreads();
  }
  if (t < nb) bsum[t] = s[t] - v;  // exclusive
  if (t == 255) bsum[nb] = s[255]; // total
}

__global__ __launch_bounds__(256) void k_scan3(const int* __restrict__ cnt, const int* __restrict__ bsum,
                                               int* __restrict__ off, int n) {
  __shared__ int s[256];
  int t = threadIdx.x;
  int i = blockIdx.x * 256 + t;
  int v = (i < n) ? cnt[i] : 0;
  s[t] = v;
  __syncthreads();
  for (int d = 1; d < 256; d <<= 1) {
    int x = (t >= d) ? s[t - d] : 0;
    __syncthreads();
    s[t] += x;
    __syncthreads();
  }
  if (i < n) off[i] = bsum[blockIdx.x] + s[t] - v;
  if (i == n - 1) off[n] = bsum[blockIdx.x] + s[t];
}

__global__ __launch_bounds__(256) void k_fill(const int* __restrict__ src, const int* __restrict__ dst,
                                              const int* __restrict__ off, const int* __restrict__ pos,
                                              int* __restrict__ ssrc, int E) {
  int e = blockIdx.x * 256 + threadIdx.x;
  if (e >= E) return;
  ssrc[off[dst[e]] + pos[e]] = src[e];
}

// ---- CSR mean-aggregate, wave-per-node: 4 lane-groups x 16 lanes.
__global__ __launch_bounds__(256) void k_aggregate(const bf16_t* __restrict__ h,
                                                   const int* __restrict__ ssrc,
                                                   const int* __restrict__ off,
                                                   bf16_t* __restrict__ agg, int n) {
  int node = blockIdx.x * 4 + (threadIdx.x >> 6);
  if (node >= n) return;
  int lane = threadIdx.x & 63;
  int g = lane >> 4;
  int fl = lane & 15;
  int b = off[node], e = off[node + 1];
  float acc[8];
#pragma unroll
  for (int j = 0; j < 8; ++j) acc[j] = 0.f;
  const bf16_t* hp = h + fl * 8;
  int i = b;
  for (; i + 16 <= e; i += 16) {
    int s0 = ssrc[i + g], s1 = ssrc[i + 4 + g], s2 = ssrc[i + 8 + g], s3 = ssrc[i + 12 + g];
    bf16x8 v0 = *(const bf16x8*)(hp + (size_t)s0 * HD);
    bf16x8 v1 = *(const bf16x8*)(hp + (size_t)s1 * HD);
    bf16x8 v2 = *(const bf16x8*)(hp + (size_t)s2 * HD);
    bf16x8 v3 = *(const bf16x8*)(hp + (size_t)s3 * HD);
#pragma unroll
    for (int j = 0; j < 8; ++j)
      acc[j] += ((float)v0[j] + (float)v1[j]) + ((float)v2[j] + (float)v3[j]);
  }
  if (i + 8 <= e) {
    int s0 = ssrc[i + g], s1 = ssrc[i + 4 + g];
    bf16x8 v0 = *(const bf16x8*)(hp + (size_t)s0 * HD);
    bf16x8 v1 = *(const bf16x8*)(hp + (size_t)s1 * HD);
#pragma unroll
    for (int j = 0; j < 8; ++j) acc[j] += (float)v0[j] + (float)v1[j];
    i += 8;
  }
  if (i + 4 <= e) {
    int s0 = ssrc[i + g];
    bf16x8 v0 = *(const bf16x8*)(hp + (size_t)s0 * HD);
#pragma unroll
    for (int j = 0; j < 8; ++j) acc[j] += (float)v0[j];
    i += 4;
  }
  if (i + g < e) {
    int s0 = ssrc[i + g];
    bf16x8 v0 = *(const bf16x8*)(hp + (size_t)s0 * HD);
#pragma unroll
    for (int j = 0; j < 8; ++j) acc[j] += (float)v0[j];
  }
#pragma unroll
  for (int j = 0; j < 8; ++j) {
    acc[j] += __shfl_xor(acc[j], 16);
    acc[j] += __shfl_xor(acc[j], 32);
  }
  if (g == 0) {
    float inv = (e > b) ? 1.f / (float)(e - b) : 0.f;
    bf16x8 o;
#pragma unroll
    for (int j = 0; j < 8; ++j) o[j] = (bf16_t)(acc[j] * inv);
    *(bf16x8*)(agg + (size_t)node * HD + fl * 8) = o;
  }
}

// ---- pool: block-per-graph, binary-search boundaries, writes mean (no atomics)
__global__ __launch_bounds__(256) void k_pool(const bf16_t* __restrict__ agg,
                                              const int* __restrict__ batch,
                                              float* __restrict__ p, int n) {
  __shared__ float s[256];
  int g = blockIdx.x;
  int t = threadIdx.x;
  int lo = 0, hi = n;
  while (lo < hi) { int m = (lo + hi) >> 1; if (batch[m] < g) lo = m + 1; else hi = m; }
  int lo2 = lo, hi2 = n;
  while (lo2 < hi2) { int m = (lo2 + hi2) >> 1; if (batch[m] < g + 1) lo2 = m + 1; else hi2 = m; }
  int count = lo2 - lo;
  int f = t & 127;
  int half = t >> 7;
  float acc = 0.f;
  for (int i = lo + half; i < lo2; i += 2)
    acc += (float)agg[(size_t)i * HD + f];
  s[t] = acc;
  __syncthreads();
  if (t < 128) {
    float v = s[t] + s[t + 128];
    float inv = (count > 0) ? 1.f / (float)count : 0.f;
    p[g * HD + t] = v * inv;
  }
}

// ---- head: z = p @ (w3*norm); out = mlp(z). One block per graph.
__global__ __launch_bounds__(128) void k_head(const float* __restrict__ p,
                                              const float* __restrict__ w3,
                                              const float* __restrict__ c1w, const float* __restrict__ c1b,
                                              const float* __restrict__ c2w, const float* __restrict__ c2b,
                                              const float* __restrict__ c3w, const float* __restrict__ c3b,
                                              float* __restrict__ out) {
  __shared__ float sa[128], sb[128];
  int g = blockIdx.x, t = threadIdx.x;
  sa[t] = p[g * HD + t];
  __syncthreads();
  float z = 0.f;
  for (int k = 0; k < HD; ++k) z += sa[k] * w3[k * HD + t];
  z *= TP_NORM_F;
  out[128 + g * HD + t] = z;
  sb[t] = z;
  __syncthreads();
  float o1 = c1b[t];
  for (int k = 0; k < HD; ++k) o1 += sb[k] * c1w[k * HD + t];
  o1 = fmaxf(o1, 0.f);
  __syncthreads();
  sa[t] = o1;
  __syncthreads();
  float o2 = c2b[t];
  for (int k = 0; k < HD; ++k) o2 += sa[k] * c2w[k * HD + t];
  o2 = fmaxf(o2, 0.f);
  __syncthreads();
  sb[t] = o2;
  __syncthreads();
  if (t < 2) {
    float o = c3b[t];
    for (int k = 0; k < HD; ++k) o += sb[k] * c3w[k * 2 + t];
    out[g * 2 + t] = o;
  }
}

extern "C" void kernel_launch(void* const* d_in, const int* in_sizes, int n_in,
                              void* d_out, int out_size, void* d_ws, size_t ws_size,
                              hipStream_t stream) {
  const float* x = (const float*)d_in[0];
  const int* eidx = (const int*)d_in[2];
  const int* src = eidx;
  const int* dst = eidx + N_EDGES;
  const int* batch = (const int*)d_in[3];
  const float* lin_w = (const float*)d_in[4];
  const float* lin_b = (const float*)d_in[5];
  const float* tp_w1 = (const float*)d_in[6];
  const float* tp_w2 = (const float*)d_in[7];
  const float* tp_w3 = (const float*)d_in[8];
  const float* c1w = (const float*)d_in[9];
  const float* c1b = (const float*)d_in[10];
  const float* c2w = (const float*)d_in[11];
  const float* c2b = (const float*)d_in[12];
  const float* c3w = (const float*)d_in[13];
  const float* c3b = (const float*)d_in[14];
  float* out = (float*)d_out;
  (void)in_sizes; (void)n_in; (void)out_size; (void)ws_size;

  uintptr_t wp = (uintptr_t)d_ws;
  auto alloc = [&](size_t bytes) -> void* {
    uintptr_t a = (wp + 255) & ~(uintptr_t)255;
    wp = a + bytes;
    return (void*)a;
  };
  bf16_t* WtL  = (bf16_t*)alloc(sizeof(bf16_t) * (size_t)HD * FIN);
  bf16_t* Wt1  = (bf16_t*)alloc(sizeof(bf16_t) * (size_t)HD * HD);
  bf16_t* Wt2  = (bf16_t*)alloc(sizeof(bf16_t) * (size_t)HD * HD);
  bf16_t* h    = (bf16_t*)alloc(sizeof(bf16_t) * (size_t)50048 * HD);
  bf16_t* agg  = (bf16_t*)alloc(sizeof(bf16_t) * (size_t)50048 * HD);
  int*    cnt  = (int*)alloc(sizeof(int) * N_NODES);
  int*    bsum = (int*)alloc(sizeof(int) * 256);
  int*    offs = (int*)alloc(sizeof(int) * (N_NODES + 1));
  int*    pos  = (int*)alloc(sizeof(int) * N_EDGES);
  int*    ssrc = (int*)alloc(sizeof(int) * N_EDGES);
  float*  pbuf = (float*)alloc(sizeof(float) * NG * HD);

  hipMemsetAsync(cnt, 0, sizeof(int) * N_NODES, stream);

  k_transpose_all<<<(FIN * HD + 2 * HD * HD + 255) / 256, 256, 0, stream>>>(
      lin_w, tp_w1, tp_w2, WtL, Wt1, Wt2);

  const int nScanBlocks = (N_NODES + 255) / 256;  // 196
  k_pos<<<(N_EDGES + 255) / 256, 256, 0, stream>>>(dst, cnt, pos, N_EDGES);
  k_scan1<<<nScanBlocks, 256, 0, stream>>>(cnt, bsum, N_NODES);
  k_scan2<<<1, 256, 0, stream>>>(bsum, nScanBlocks);
  k_scan3<<<nScanBlocks, 256, 0, stream>>>(cnt, bsum, offs, N_NODES);
  k_fill<<<(N_EDGES + 255) / 256, 256, 0, stream>>>(src, dst, offs, pos, ssrc, N_EDGES);

  const int gblocks = (N_NODES + 31) / 32;   // 1563
  const int ablocks = (N_NODES + 3) / 4;     // 12500

  // h0 = relu(x @ lin_w + b)
  k_gemm1<<<gblocks, 256, 0, stream>>>(x, WtL, lin_b, h, N_NODES, FIN);

  // conv1
  k_aggregate<<<ablocks, 256, 0, stream>>>(h, ssrc, offs, agg, N_NODES);
  k_gemm_conv<<<gblocks, 256, 0, stream>>>(agg, Wt1, h, N_NODES, 1);
  // conv2
  k_aggregate<<<ablocks, 256, 0, stream>>>(h, ssrc, offs, agg, N_NODES);
  k_gemm_conv<<<gblocks, 256, 0, stream>>>(agg, Wt2, h, N_NODES, 1);
  // conv3 aggregation only (W3 folded into head)
  k_aggregate<<<ablocks, 256, 0, stream>>>(h, ssrc, offs, agg, N_NODES);

  k_pool<<<NG, 256, 0, stream>>>(agg, batch, pbuf, N_NODES);
  k_head<<<NG, 128, 0, stream>>>(pbuf, tp_w3, c1w, c1b, c2w, c2b, c3w, c3b, out);
}